// Round 5
// baseline (820.863 us; speedup 1.0000x reference)
//
#include <hip/hip_runtime.h>

#define CRF_B 512
#define CRF_T 2048
#define CRF_K 32
#define CRF_Q (CRF_T / 4)   // 512 packed-bp dwords per batch per column

// Lane layout: rows r = l>>4 (16 lanes each), col c = l&15.
// Alternating hold patterns (value vstate = s[a_phase]):
//   pattern A (start of odd steps): rows {0,1} hold s[c],   rows {2,3} hold s[16+c]  -> aA = 16*(r>>1)+c
//   pattern B (start of even steps): rows {0,2} hold s[c],  rows {1,3} hold s[16+c]  -> aB = 16*(r&1)+c
// Phase A step: row reduces half hA=r>>1 (the half it holds), combine partners rows 0<->2, 1<->3
//   (lane^32), computing output jA = 16*(r&1)+c = aB  => winner lands already in pattern B. 
// Phase B step: hB=r&1, partners rows 0<->1, 2<->3 (lane^16), output jB = 16*(r>>1)+c = aA
//   => winner lands in pattern A. ONE cross-lane exchange per step; gather is DPP row_ror (VALU).
// Rows 0 and 3 have jA == jB, so they hold a phase-consistent output column and store the
// packed bp dword; backtrack layout is identical to the verified R2 kernel.

__device__ __forceinline__ void crf_step(
    float& vstate, unsigned int& bpack, int sx,
    const float (&trp)[16], const unsigned int (&bpos)[16],
    int hphase, int xmask, float curv)
{
    // gather + add: val[m] = s[idx_phase[m]] + trans[idx_phase[m]][j_phase]  (all VALU)
    float val[16];
    val[0] = vstate + trp[0];
#define CRF_GA(m) { int _rb = __builtin_amdgcn_update_dpp(0, __float_as_int(vstate), 0x120 + (m), 0xF, 0xF, false); \
                    val[m] = __int_as_float(_rb) + trp[m]; }
    CRF_GA(1) CRF_GA(2) CRF_GA(3) CRF_GA(4) CRF_GA(5) CRF_GA(6) CRF_GA(7)
    CRF_GA(8) CRF_GA(9) CRF_GA(10) CRF_GA(11) CRF_GA(12) CRF_GA(13) CRF_GA(14) CRF_GA(15)
#undef CRF_GA
    // value-only max tree (clang may fuse to v_max3)
    float t8[8];
#pragma unroll
    for (int k = 0; k < 8; ++k) t8[k] = fmaxf(val[k], val[k + 8]);
    float t4[4];
#pragma unroll
    for (int k = 0; k < 4; ++k) t4[k] = fmaxf(t8[k], t8[k + 4]);
    float vmax = fmaxf(fmaxf(t4[0], t4[2]), fmaxf(t4[1], t4[3]));
    // exact first-index argmax within half: match-mask, msb = lowest local index
    unsigned int bm = 0u;
#pragma unroll
    for (int m = 0; m < 16; ++m) bm |= (val[m] == vmax) ? bpos[m] : 0u;
    int myi = (__clz((int)bm) - 16) + (hphase << 4);   // global source index of half-winner

    // cross-half combine: partner differs only in reduced half; tie -> h=0 side (lower i)
    float pv = __shfl_xor(vmax, xmask, 64);
    int   pi = __shfl_xor(myi, xmask, 64);
    bool take = hphase ? (pv >= vmax) : (pv > vmax);
    float w  = take ? pv : vmax;   // both partners end with the same winner
    int   wi = take ? pi : myi;
    bpack |= ((unsigned int)wi) << (8 * sx);
    vstate = w + curv;             // lands directly in the next phase's hold pattern
}

__global__ __launch_bounds__(64, 1) void crf_fused(
    const float* __restrict__ pot,    // [B,T,K]
    const float* __restrict__ trans,  // [K,K]
    float* __restrict__ out,          // [B,T,K] one-hot fp32
    unsigned int* __restrict__ bp)    // ws: [B, Q, K] packed backpointers
{
    const int b = blockIdx.x;
    const int l = threadIdx.x;
    const int c = l & 15;
    const int r = l >> 4;
    const int aA = ((r >> 1) << 4) | c;   // held index at start of phase-A (odd t) steps
    const int aB = ((r & 1) << 4) | c;    // held index at start of phase-B (even t) steps
    const int jA = aB;                    // output column computed during phase A
    const int hA = r >> 1;                // half reduced during phase A
    const int hB = r & 1;                 // half reduced during phase B

    // source-index tables via the SAME dpp applied to the seed (ror-direction-proof)
    int idxA[16], idxB[16];
    idxA[0] = aA; idxB[0] = aB;
#define CRF_IDX(m) \
    idxA[m] = __builtin_amdgcn_update_dpp(0, aA, 0x120 + (m), 0xF, 0xF, false); \
    idxB[m] = __builtin_amdgcn_update_dpp(0, aB, 0x120 + (m), 0xF, 0xF, false);
    CRF_IDX(1) CRF_IDX(2) CRF_IDX(3) CRF_IDX(4) CRF_IDX(5) CRF_IDX(6) CRF_IDX(7)
    CRF_IDX(8) CRF_IDX(9) CRF_IDX(10) CRF_IDX(11) CRF_IDX(12) CRF_IDX(13) CRF_IDX(14) CRF_IDX(15)
#undef CRF_IDX

    float trA[16], trB[16];      // trans slices per phase: trans[idx][j_phase]
    unsigned int bpos[16];       // bit (15 - local idx): low nibble identical for A/B
#pragma unroll
    for (int m = 0; m < 16; ++m) {
        trA[m]  = trans[idxA[m] * CRF_K + aB];   // jA == aB
        trB[m]  = trans[idxB[m] * CRF_K + aA];   // jB == aA
        bpos[m] = 1u << (15 - (idxA[m] & 15));
    }

    const float* potb = pot + (size_t)b * (CRF_T * CRF_K);
    unsigned int* bpb = bp + (size_t)b * (CRF_Q * CRF_K);
    float* outb = out + (size_t)b * (CRF_T * CRF_K);

    // pot address per sx: step t ends in pattern B for odd sx (phase A), pattern A for even sx
    const int aoff[4] = { aA, aB, aA, aB };

    float vstate = potb[aA];           // t = 0, pattern A (step 1 is phase A)

    // potential triple-buffer: 2-q-iter prefetch lead
    float cur[4], nxt[4], nx2[4];
    cur[0] = 0.0f;                     // never read (q==0, sx==0 skipped)
#pragma unroll
    for (int t = 1; t < 4; ++t) cur[t] = potb[t * CRF_K + aoff[t]];
#pragma unroll
    for (int sx = 0; sx < 4; ++sx) nxt[sx] = potb[(4 + sx) * CRF_K + aoff[sx]];

    for (int q = 0; q < CRF_Q; ++q) {
        {
            const int tb = (q + 2) * 4;
#pragma unroll
            for (int sx = 0; sx < 4; ++sx) {
                int t = tb + sx; if (t > CRF_T - 1) t = CRF_T - 1;
                nx2[sx] = potb[t * CRF_K + aoff[sx]];
            }
        }
        unsigned int bpack = 0;
        if (q)  crf_step(vstate, bpack, 0, trB, bpos, hB, 16, cur[0]);  // t=4q   phase B
        crf_step(vstate, bpack, 1, trA, bpos, hA, 32, cur[1]);          // t=4q+1 phase A
        crf_step(vstate, bpack, 2, trB, bpos, hB, 16, cur[2]);          // t=4q+2 phase B
        crf_step(vstate, bpack, 3, trA, bpos, hA, 32, cur[3]);          // t=4q+3 phase A
        // rows 0,3 have phase-consistent output column jA(==jB): they own the bp dword
        if (r == 0 || r == 3) bpb[q * CRF_K + jA] = bpack;
#pragma unroll
        for (int sx = 0; sx < 4; ++sx) { cur[sx] = nxt[sx]; nxt[sx] = nx2[sx]; }
    }

    // ---------------- last tag (argmax over final state, first-index ties) ----------------
    __shared__ float fs[CRF_K];
    fs[aB] = vstate;                  // last step was phase A -> pattern B; 2 lanes/slot, same value
    __syncthreads();
    int bt = 0; float bv = fs[0];
#pragma unroll
    for (int jj = 1; jj < CRF_K; ++jj) {
        float v = fs[jj];
        if (v > bv) { bv = v; bt = jj; }
    }
    int stag = __builtin_amdgcn_readfirstlane(bt);

    const int col = l & 31;
    // one-hot row for t = T-1 (halves write identical 128B row)
    outb[(CRF_T - 1) * CRF_K + col] = (col == stag) ? 1.0f : 0.0f;

    __threadfence();   // make own bp stores visible before read-back

    // ---------------- backtrack: lane col holds COLUMN col of bp ----------------
    for (int q0 = CRF_Q - 16; q0 >= 0; q0 -= 16) {
        unsigned int colv[16];
#pragma unroll
        for (int rr = 0; rr < 16; ++rr) colv[rr] = bpb[(q0 + rr) * CRF_K + col];
#pragma unroll
        for (int rr = 15; rr >= 0; --rr) {
#pragma unroll
            for (int bi = 3; bi >= 0; --bi) {
                const int t = (q0 + rr) * 4 + bi;
                if (t == 0) continue;   // only q0==0, rr==0, bi==0
                unsigned int dw = (unsigned int)__builtin_amdgcn_readlane((int)colv[rr], stag);
                stag = (int)((dw >> (8 * bi)) & 255u);
                outb[(size_t)(t - 1) * CRF_K + col] = (col == stag) ? 1.0f : 0.0f;
            }
        }
    }
}

extern "C" void kernel_launch(void* const* d_in, const int* in_sizes, int n_in,
                              void* d_out, int out_size, void* d_ws, size_t ws_size,
                              hipStream_t stream) {
    const float* pot   = (const float*)d_in[0];   // inputs [512,2048,32] fp32
    const float* trans = (const float*)d_in[1];   // transitions [32,32] fp32
    float* out = (float*)d_out;
    unsigned int* bp = (unsigned int*)d_ws;       // needs 33,554,432 B

    crf_fused<<<dim3(CRF_B), dim3(64), 0, stream>>>(pot, trans, out, bp);
}

// Round 6
// 820.638 us; speedup vs baseline: 1.0003x; 1.0003x over previous
//
#include <hip/hip_runtime.h>

#define CRF_B 512
#define CRF_T 2048
#define CRF_K 32
#define CRF_Q (CRF_T / 4)   // 512 packed-bp dwords per batch per column

// Lane layout: rows r = l>>4 (16 lanes each), col c = l&15.
// Alternating hold patterns (vstate = s[a_phase]):
//   pattern A (start of odd steps):  rows {0,1} hold s[c], rows {2,3} hold s[16+c]; aA = 16*(r>>1)+c
//   pattern B (start of even steps): rows {0,2} hold s[c], rows {1,3} hold s[16+c]; aB = 16*(r&1)+c
// Phase A step: lane reduces half hA=r>>1, combine partner l^32, output jA = aB (lands in pattern B).
// Phase B step: lane reduces half hB=r&1,  combine partner l^16, output jB = aA (lands in pattern A).
//
// CRITICAL-CHAIN DISCIPLINE (the R6 change): the recurrence consumes ONLY the max value —
// gather(DPP) -> fmax tree -> ONE shfl_xor(vmax) -> fmax -> +pot. The argmax (VCC-serialized
// match-mask + clz) and the winner-half bit W hang off the chain as pure store-path work:
// each lane contributes its packed 5-bit code ((idx4<<1)|W) only if its OWN half won (loser
// contributes 0), so the index never crosses lanes per step. Once per q, two off-chain
// masked shfl-ORs assemble the bp dword from the partner lanes.

__device__ __forceinline__ void crf_step(
    float& vstate, unsigned int& bpOwn, int sx,
    const float (&trp)[16], const unsigned int (&bpos)[16],
    int hbit, int xmask, float curv)
{
    // gather + add: val[m] = s[idx_phase[m]] + trans[idx_phase[m]][j_phase]  (all VALU)
    float val[16];
    val[0] = vstate + trp[0];
#define CRF_GA(m) { int _rb = __builtin_amdgcn_update_dpp(0, __float_as_int(vstate), 0x120 + (m), 0xF, 0xF, false); \
                    val[m] = __int_as_float(_rb) + trp[m]; }
    CRF_GA(1) CRF_GA(2) CRF_GA(3) CRF_GA(4) CRF_GA(5) CRF_GA(6) CRF_GA(7)
    CRF_GA(8) CRF_GA(9) CRF_GA(10) CRF_GA(11) CRF_GA(12) CRF_GA(13) CRF_GA(14) CRF_GA(15)
#undef CRF_GA
    // value-only max tree (clang may fuse to v_max3)
    float t8[8];
#pragma unroll
    for (int k = 0; k < 8; ++k) t8[k] = fmaxf(val[k], val[k + 8]);
    float t4[4];
#pragma unroll
    for (int k = 0; k < 4; ++k) t4[k] = fmaxf(t8[k], t8[k + 4]);
    float vmax = fmaxf(fmaxf(t4[0], t4[2]), fmaxf(t4[1], t4[3]));

    // CHAIN: single cross-half value exchange; recurrence closes with fmax + add.
    float pv = __shfl_xor(vmax, xmask, 64);
    float w  = fmaxf(vmax, pv);
    vstate = w + curv;

    // OFF-CHAIN (store path only; independent of pv except the 1-cmp W bit):
    // within-half first-index argmax via match-mask + clz (exact, proven R5 machinery)
    unsigned int bm = 0u;
#pragma unroll
    for (int m = 0; m < 16; ++m) bm |= (val[m] == vmax) ? bpos[m] : 0u;
    unsigned int idx4 = (unsigned int)(__clz((int)bm) - 16);   // local index in [0,16)
    // winner-half bit W = (half1max > half0max): identical on both partners; tie -> half0
    bool W = hbit ? (vmax > pv) : (pv > vmax);
    bool own_won = (W == (hbit != 0));
    unsigned int contrib = own_won ? ((idx4 << 1) | (W ? 1u : 0u)) : 0u;
    bpOwn |= contrib << (8 * sx);
}

__global__ __launch_bounds__(64, 1) void crf_fused(
    const float* __restrict__ pot,    // [B,T,K]
    const float* __restrict__ trans,  // [K,K]
    float* __restrict__ out,          // [B,T,K] one-hot fp32
    unsigned int* __restrict__ bp)    // ws: [B, Q, K] packed backpointers
{
    const int b = blockIdx.x;
    const int l = threadIdx.x;
    const int c = l & 15;
    const int r = l >> 4;
    const int aA = ((r >> 1) << 4) | c;   // held index at start of phase-A (odd t) steps
    const int aB = ((r & 1) << 4) | c;    // held index at start of phase-B (even t) steps
    const int jA = aB;                    // output column (phase A); == jB for rows 0,3
    const int hA = r >> 1;                // half reduced during phase A
    const int hB = r & 1;                 // half reduced during phase B

    // source-index tables via the SAME dpp applied to the seed (ror-direction-proof)
    int idxA[16], idxB[16];
    idxA[0] = aA; idxB[0] = aB;
#define CRF_IDX(m) \
    idxA[m] = __builtin_amdgcn_update_dpp(0, aA, 0x120 + (m), 0xF, 0xF, false); \
    idxB[m] = __builtin_amdgcn_update_dpp(0, aB, 0x120 + (m), 0xF, 0xF, false);
    CRF_IDX(1) CRF_IDX(2) CRF_IDX(3) CRF_IDX(4) CRF_IDX(5) CRF_IDX(6) CRF_IDX(7)
    CRF_IDX(8) CRF_IDX(9) CRF_IDX(10) CRF_IDX(11) CRF_IDX(12) CRF_IDX(13) CRF_IDX(14) CRF_IDX(15)
#undef CRF_IDX

    float trA[16], trB[16];      // trans slices per phase: trans[idx][j_phase]
    unsigned int bpos[16];       // bit (15 - local idx); low nibble identical for A/B seeds
#pragma unroll
    for (int m = 0; m < 16; ++m) {
        trA[m]  = trans[idxA[m] * CRF_K + aB];   // jA == aB
        trB[m]  = trans[idxB[m] * CRF_K + aA];   // jB == aA
        bpos[m] = 1u << (15 - (idxA[m] & 15));
    }

    const float* potb = pot + (size_t)b * (CRF_T * CRF_K);
    unsigned int* bpb = bp + (size_t)b * (CRF_Q * CRF_K);
    float* outb = out + (size_t)b * (CRF_T * CRF_K);

    // pot address per sx: step t ends in pattern B for odd sx (phase A), pattern A for even sx
    const int aoff[4] = { aA, aB, aA, aB };

    float vstate = potb[aA];           // t = 0, pattern A (step 1 is phase A)

    // potential triple-buffer: 2-q-iter prefetch lead
    float cur[4], nxt[4], nx2[4];
    cur[0] = 0.0f;                     // never read (q==0, sx==0 skipped)
#pragma unroll
    for (int t = 1; t < 4; ++t) cur[t] = potb[t * CRF_K + aoff[t]];
#pragma unroll
    for (int sx = 0; sx < 4; ++sx) nxt[sx] = potb[(4 + sx) * CRF_K + aoff[sx]];

    for (int q = 0; q < CRF_Q; ++q) {
        {
            const int tb = (q + 2) * 4;
#pragma unroll
            for (int sx = 0; sx < 4; ++sx) {
                int t = tb + sx; if (t > CRF_T - 1) t = CRF_T - 1;
                nx2[sx] = potb[t * CRF_K + aoff[sx]];
            }
        }
        unsigned int bpOwn = 0;
        if (q)  crf_step(vstate, bpOwn, 0, trB, bpos, hB, 16, cur[0]);  // t=4q   phase B
        crf_step(vstate, bpOwn, 1, trA, bpos, hA, 32, cur[1]);          // t=4q+1 phase A
        crf_step(vstate, bpOwn, 2, trB, bpos, hB, 16, cur[2]);          // t=4q+2 phase B
        crf_step(vstate, bpOwn, 3, trA, bpos, hA, 32, cur[3]);          // t=4q+3 phase A

        // assemble the bp dword for this lane's column from partner contributions:
        //   even-sx bytes (phase B) live on the ^16 pair; odd-sx bytes (phase A) on the ^32 pair.
        unsigned int p16v = (unsigned int)__shfl_xor((int)bpOwn, 16, 64);
        unsigned int p32v = (unsigned int)__shfl_xor((int)bpOwn, 32, 64);
        unsigned int dword = bpOwn | (p16v & 0x00FF00FFu) | (p32v & 0xFF00FF00u);
        // rows 0,3 have phase-consistent output column (jA == jB): they own the store
        if (r == 0 || r == 3) bpb[q * CRF_K + jA] = dword;
#pragma unroll
        for (int sx = 0; sx < 4; ++sx) { cur[sx] = nxt[sx]; nxt[sx] = nx2[sx]; }
    }

    // ---------------- last tag (argmax over final state, first-index ties) ----------------
    __shared__ float fs[CRF_K];
    fs[aB] = vstate;                  // last step was phase A -> pattern B; 2 lanes/slot, same value
    __syncthreads();
    int bt = 0; float bv = fs[0];
#pragma unroll
    for (int jj = 1; jj < CRF_K; ++jj) {
        float v = fs[jj];
        if (v > bv) { bv = v; bt = jj; }
    }
    int stag = __builtin_amdgcn_readfirstlane(bt);

    const int col = l & 31;
    // one-hot row for t = T-1 (halves write identical 128B row)
    outb[(CRF_T - 1) * CRF_K + col] = (col == stag) ? 1.0f : 0.0f;

    __threadfence();   // make own bp stores visible before read-back

    // ---------------- backtrack: lane col holds COLUMN col of bp ----------------
    for (int q0 = CRF_Q - 16; q0 >= 0; q0 -= 16) {
        unsigned int colv[16];
#pragma unroll
        for (int rr = 0; rr < 16; ++rr) colv[rr] = bpb[(q0 + rr) * CRF_K + col];
#pragma unroll
        for (int rr = 15; rr >= 0; --rr) {
#pragma unroll
            for (int bi = 3; bi >= 0; --bi) {
                const int t = (q0 + rr) * 4 + bi;
                if (t == 0) continue;   // only q0==0, rr==0, bi==0
                unsigned int dw = (unsigned int)__builtin_amdgcn_readlane((int)colv[rr], stag);
                unsigned int byt = (dw >> (8 * bi)) & 255u;
                // decode 5-bit code: tag = idx4 + 16*W
                stag = (int)(((byt >> 1) & 15u) | ((byt & 1u) << 4));
                outb[(size_t)(t - 1) * CRF_K + col] = (col == stag) ? 1.0f : 0.0f;
            }
        }
    }
}

extern "C" void kernel_launch(void* const* d_in, const int* in_sizes, int n_in,
                              void* d_out, int out_size, void* d_ws, size_t ws_size,
                              hipStream_t stream) {
    const float* pot   = (const float*)d_in[0];   // inputs [512,2048,32] fp32
    const float* trans = (const float*)d_in[1];   // transitions [32,32] fp32
    float* out = (float*)d_out;
    unsigned int* bp = (unsigned int*)d_ws;       // needs 33,554,432 B

    crf_fused<<<dim3(CRF_B), dim3(64), 0, stream>>>(pot, trans, out, bp);
}

// Round 7
// 665.797 us; speedup vs baseline: 1.2329x; 1.2326x over previous
//
#include <hip/hip_runtime.h>

#define CRF_B 512
#define CRF_T 2048
#define CRF_K 32
#define CRF_Q (CRF_T / 4)   // 512 packed-bp dwords per batch per column

// ======================================================================
// Decomposition:
//   A) crf_fwd : serial max-plus scan, VALUES ONLY, stores every state row
//                into `out` (used as [B][T][K] f32 scratch; overwritten by C).
//   B) crf_bpk : recomputes bp[t][j] = argmax_i(s_{t-1}[i]+tr[i][j]) for all t
//                from the stored states — embarrassingly parallel (16384 waves).
//   C) crf_bt  : last-tag + backtrack + one-hot writes (overwrites scratch).
// Exactness: B consumes bit-exact stored f32 states and uses the R6-proven
// first-index tie machinery, so bp is identical to a fused forward pass.
// ======================================================================

// Lane layout (shared): rows r = l>>4 of 16 lanes, col c = l&15.
//   pattern A: rows {0,1} hold s[c], rows {2,3} hold s[16+c]; aA = 16*(r>>1)+c
//   pattern B: rows {0,2} hold s[c], rows {1,3} hold s[16+c]; aB = 16*(r&1)+c
// Phase A step (odd t): reduce half hA=r>>1, combine across ^32, land pattern B.
// Phase B step (even t): reduce half hB=r&1, combine across ^16, land pattern A.

#define CRF_GATHER16(vsrc, trp, val)                                              \
    val[0] = (vsrc) + trp[0];                                                     \
    { int _rb;                                                                    \
      _rb = __builtin_amdgcn_update_dpp(0, __float_as_int(vsrc), 0x121, 0xF, 0xF, false); val[1]  = __int_as_float(_rb) + trp[1];  \
      _rb = __builtin_amdgcn_update_dpp(0, __float_as_int(vsrc), 0x122, 0xF, 0xF, false); val[2]  = __int_as_float(_rb) + trp[2];  \
      _rb = __builtin_amdgcn_update_dpp(0, __float_as_int(vsrc), 0x123, 0xF, 0xF, false); val[3]  = __int_as_float(_rb) + trp[3];  \
      _rb = __builtin_amdgcn_update_dpp(0, __float_as_int(vsrc), 0x124, 0xF, 0xF, false); val[4]  = __int_as_float(_rb) + trp[4];  \
      _rb = __builtin_amdgcn_update_dpp(0, __float_as_int(vsrc), 0x125, 0xF, 0xF, false); val[5]  = __int_as_float(_rb) + trp[5];  \
      _rb = __builtin_amdgcn_update_dpp(0, __float_as_int(vsrc), 0x126, 0xF, 0xF, false); val[6]  = __int_as_float(_rb) + trp[6];  \
      _rb = __builtin_amdgcn_update_dpp(0, __float_as_int(vsrc), 0x127, 0xF, 0xF, false); val[7]  = __int_as_float(_rb) + trp[7];  \
      _rb = __builtin_amdgcn_update_dpp(0, __float_as_int(vsrc), 0x128, 0xF, 0xF, false); val[8]  = __int_as_float(_rb) + trp[8];  \
      _rb = __builtin_amdgcn_update_dpp(0, __float_as_int(vsrc), 0x129, 0xF, 0xF, false); val[9]  = __int_as_float(_rb) + trp[9];  \
      _rb = __builtin_amdgcn_update_dpp(0, __float_as_int(vsrc), 0x12A, 0xF, 0xF, false); val[10] = __int_as_float(_rb) + trp[10]; \
      _rb = __builtin_amdgcn_update_dpp(0, __float_as_int(vsrc), 0x12B, 0xF, 0xF, false); val[11] = __int_as_float(_rb) + trp[11]; \
      _rb = __builtin_amdgcn_update_dpp(0, __float_as_int(vsrc), 0x12C, 0xF, 0xF, false); val[12] = __int_as_float(_rb) + trp[12]; \
      _rb = __builtin_amdgcn_update_dpp(0, __float_as_int(vsrc), 0x12D, 0xF, 0xF, false); val[13] = __int_as_float(_rb) + trp[13]; \
      _rb = __builtin_amdgcn_update_dpp(0, __float_as_int(vsrc), 0x12E, 0xF, 0xF, false); val[14] = __int_as_float(_rb) + trp[14]; \
      _rb = __builtin_amdgcn_update_dpp(0, __float_as_int(vsrc), 0x12F, 0xF, 0xF, false); val[15] = __int_as_float(_rb) + trp[15]; }

#define CRF_MAXTREE(val, vmax)                                                    \
    { float _t8[8], _t4[4];                                                       \
      _Pragma("unroll") for (int _k = 0; _k < 8; ++_k) _t8[_k] = fmaxf(val[_k], val[_k + 8]); \
      _Pragma("unroll") for (int _k = 0; _k < 4; ++_k) _t4[_k] = fmaxf(_t8[_k], _t8[_k + 4]); \
      vmax = fmaxf(fmaxf(_t4[0], _t4[2]), fmaxf(_t4[1], _t4[3])); }

#define CRF_IDXTAB(seed, idx)                                                     \
    idx[0] = (seed);                                                              \
    idx[1]  = __builtin_amdgcn_update_dpp(0, (seed), 0x121, 0xF, 0xF, false);     \
    idx[2]  = __builtin_amdgcn_update_dpp(0, (seed), 0x122, 0xF, 0xF, false);     \
    idx[3]  = __builtin_amdgcn_update_dpp(0, (seed), 0x123, 0xF, 0xF, false);     \
    idx[4]  = __builtin_amdgcn_update_dpp(0, (seed), 0x124, 0xF, 0xF, false);     \
    idx[5]  = __builtin_amdgcn_update_dpp(0, (seed), 0x125, 0xF, 0xF, false);     \
    idx[6]  = __builtin_amdgcn_update_dpp(0, (seed), 0x126, 0xF, 0xF, false);     \
    idx[7]  = __builtin_amdgcn_update_dpp(0, (seed), 0x127, 0xF, 0xF, false);     \
    idx[8]  = __builtin_amdgcn_update_dpp(0, (seed), 0x128, 0xF, 0xF, false);     \
    idx[9]  = __builtin_amdgcn_update_dpp(0, (seed), 0x129, 0xF, 0xF, false);     \
    idx[10] = __builtin_amdgcn_update_dpp(0, (seed), 0x12A, 0xF, 0xF, false);     \
    idx[11] = __builtin_amdgcn_update_dpp(0, (seed), 0x12B, 0xF, 0xF, false);     \
    idx[12] = __builtin_amdgcn_update_dpp(0, (seed), 0x12C, 0xF, 0xF, false);     \
    idx[13] = __builtin_amdgcn_update_dpp(0, (seed), 0x12D, 0xF, 0xF, false);     \
    idx[14] = __builtin_amdgcn_update_dpp(0, (seed), 0x12E, 0xF, 0xF, false);     \
    idx[15] = __builtin_amdgcn_update_dpp(0, (seed), 0x12F, 0xF, 0xF, false);

// ---------------- Kernel A: lean serial forward (values only) ----------------
__global__ __launch_bounds__(64, 1) void crf_fwd(
    const float* __restrict__ pot,    // [B,T,K]
    const float* __restrict__ trans,  // [K,K]
    float* __restrict__ st)           // [B,T,K] state scratch (= out buffer)
{
    const int b = blockIdx.x;
    const int l = threadIdx.x;
    const int c = l & 15;
    const int r = l >> 4;
    const int aA = ((r >> 1) << 4) | c;
    const int aB = ((r & 1) << 4) | c;

    int idxA[16], idxB[16];
    CRF_IDXTAB(aA, idxA)
    CRF_IDXTAB(aB, idxB)

    float trA[16], trB[16];
#pragma unroll
    for (int m = 0; m < 16; ++m) {
        trA[m] = trans[idxA[m] * CRF_K + aB];   // phase A output column = aB
        trB[m] = trans[idxB[m] * CRF_K + aA];   // phase B output column = aA
    }

    // permlane32_swap direction probe: per-lane, which return slot is the partner?
    auto pr = __builtin_amdgcn_permlane32_swap((unsigned)l, (unsigned)l, false, false);
    const bool use0 = ((int)pr[0] == (l ^ 32));

    const float* potb = pot + (size_t)b * (CRF_T * CRF_K);
    float* stb = st + (size_t)b * (CRF_T * CRF_K);

    float vstate = potb[aA];          // t = 0, pattern A
    stb[aA] = vstate;                 // store s_0 (dup lanes: same addr, same value)

    float cur[4], nxt[4], nx2[4];
    cur[0] = 0.0f;                    // never read (q==0, sx==0 skipped)
#pragma unroll
    for (int t = 1; t < 4; ++t) cur[t] = potb[t * CRF_K + ((t & 1) ? aB : aA)];
#pragma unroll
    for (int sx = 0; sx < 4; ++sx) nxt[sx] = potb[(4 + sx) * CRF_K + ((sx & 1) ? aB : aA)];

    for (int q = 0; q < CRF_Q; ++q) {
        {
            const int tb = (q + 2) * 4;
#pragma unroll
            for (int sx = 0; sx < 4; ++sx) {
                int t = tb + sx; if (t > CRF_T - 1) t = CRF_T - 1;
                nx2[sx] = potb[t * CRF_K + ((sx & 1) ? aB : aA)];
            }
        }
        // t = 4q : phase B (^16 via ds_swizzle), lands pattern A
        if (q) {
            float val[16], vmax;
            CRF_GATHER16(vstate, trB, val)
            CRF_MAXTREE(val, vmax)
            float pv = __int_as_float(__builtin_amdgcn_ds_swizzle(__float_as_int(vmax), 0x401F));
            vstate = fmaxf(vmax, pv) + cur[0];
            stb[(4 * q) * CRF_K + aA] = vstate;
        }
        // t = 4q+1 : phase A (^32 via permlane32_swap), lands pattern B
        {
            float val[16], vmax;
            CRF_GATHER16(vstate, trA, val)
            CRF_MAXTREE(val, vmax)
            auto sw = __builtin_amdgcn_permlane32_swap(__float_as_uint(vmax), __float_as_uint(vmax), false, false);
            float pv = __uint_as_float(use0 ? (unsigned)sw[0] : (unsigned)sw[1]);
            vstate = fmaxf(vmax, pv) + cur[1];
            stb[(4 * q + 1) * CRF_K + aB] = vstate;
        }
        // t = 4q+2 : phase B
        {
            float val[16], vmax;
            CRF_GATHER16(vstate, trB, val)
            CRF_MAXTREE(val, vmax)
            float pv = __int_as_float(__builtin_amdgcn_ds_swizzle(__float_as_int(vmax), 0x401F));
            vstate = fmaxf(vmax, pv) + cur[2];
            stb[(4 * q + 2) * CRF_K + aA] = vstate;
        }
        // t = 4q+3 : phase A
        {
            float val[16], vmax;
            CRF_GATHER16(vstate, trA, val)
            CRF_MAXTREE(val, vmax)
            auto sw = __builtin_amdgcn_permlane32_swap(__float_as_uint(vmax), __float_as_uint(vmax), false, false);
            float pv = __uint_as_float(use0 ? (unsigned)sw[0] : (unsigned)sw[1]);
            vstate = fmaxf(vmax, pv) + cur[3];
            stb[(4 * q + 3) * CRF_K + aB] = vstate;
        }
#pragma unroll
        for (int sx = 0; sx < 4; ++sx) { cur[sx] = nxt[sx]; nxt[sx] = nx2[sx]; }
    }
}

// ---------------- Kernel B: parallel bp recompute from stored states ----------------
// Block (b, k) handles q in [16k, 16k+16) i.e. t in [64k, 64k+63] (t=0 skipped).
// Fixed pattern-B layout every step (state loaded fresh from memory).
__global__ __launch_bounds__(64, 1) void crf_bpk(
    const float* __restrict__ st,     // [B,T,K] states
    const float* __restrict__ trans,  // [K,K]
    unsigned int* __restrict__ bp)    // [B,Q,K] packed backpointers
{
    const int blk = blockIdx.x;
    const int b = blk >> 5;
    const int k = blk & 31;
    const int l = threadIdx.x;
    const int c = l & 15;
    const int r = l >> 4;
    const int h = r & 1;
    const int aB = (h << 4) | c;          // gathered state index
    const int j = ((r >> 1) << 4) | c;    // output column

    int idxB[16];
    CRF_IDXTAB(aB, idxB)
    float trB[16]; unsigned int bpos[16];
#pragma unroll
    for (int m = 0; m < 16; ++m) {
        trB[m]  = trans[idxB[m] * CRF_K + j];
        bpos[m] = 1u << (15 - (idxB[m] & 15));
    }

    const float* stb = st + (size_t)b * (CRF_T * CRF_K);
    unsigned int* bpb = bp + (size_t)b * (CRF_Q * CRF_K);

    const int q0 = k * 16;
    const int t_first = (q0 == 0) ? 1 : 4 * q0;
    float snext = stb[(t_first - 1) * CRF_K + aB];   // s_{t-1} for first executed step

    for (int q = q0; q < q0 + 16; ++q) {
        unsigned int dword = 0;
#pragma unroll
        for (int sx = 0; sx < 4; ++sx) {
            const int t = 4 * q + sx;
            if (q == 0 && sx == 0) continue;          // t=0 has no backpointer
            float s = snext;
            {   // rolling 1-ahead prefetch of the next state row (clamped tail reload)
                int tn = t + 1; if (tn > CRF_T - 1) tn = CRF_T - 1;
                snext = stb[(tn - 1) * CRF_K + aB];
            }
            float val[16], vmax;
            CRF_GATHER16(s, trB, val)
            CRF_MAXTREE(val, vmax)
            unsigned int bm = 0u;
#pragma unroll
            for (int m = 0; m < 16; ++m) bm |= (val[m] == vmax) ? bpos[m] : 0u;
            unsigned int idx4 = (unsigned int)(__clz((int)bm) - 16);  // local first-index
            float pv = __int_as_float(__builtin_amdgcn_ds_swizzle(__float_as_int(vmax), 0x401F));
            bool W = h ? (vmax > pv) : (pv > vmax);   // half1 strictly beats half0?
            bool own_won = (W == (h != 0));           // tie -> half0 (lower indices)
            unsigned int byte = own_won ? (idx4 | ((unsigned)h << 4)) : 0u;
            dword |= byte << (8 * sx);
        }
        // merge partner bytes (losing side contributed 0); partners are l^16
        dword |= (unsigned int)__builtin_amdgcn_ds_swizzle((int)dword, 0x401F);
        bpb[q * CRF_K + j] = dword;   // dup lanes: same addr, same value (benign)
    }
}

// ---------------- Kernel C: last-tag + backtrack + one-hot ----------------
__global__ __launch_bounds__(64, 1) void crf_bt(
    const unsigned int* __restrict__ bp,  // [B,Q,K]
    float* out)                            // [B,T,K]: holds states on entry, one-hot on exit
{
    const int b = blockIdx.x;
    const int l = threadIdx.x;
    const int col = l & 31;

    float* outb = out + (size_t)b * (CRF_T * CRF_K);
    const unsigned int* bpb = bp + (size_t)b * (CRF_Q * CRF_K);

    // read final state row BEFORE overwriting the scratch
    float fv = outb[(CRF_T - 1) * CRF_K + col];
    __shared__ float fs[CRF_K];
    fs[col] = fv;                       // dup lanes write same value (benign)
    __syncthreads();
    int bt = 0; float bv = fs[0];
#pragma unroll
    for (int jj = 1; jj < CRF_K; ++jj) {
        float v = fs[jj];
        if (v > bv) { bv = v; bt = jj; }
    }
    int stag = __builtin_amdgcn_readfirstlane(bt);

    // one-hot row for t = T-1 (halves write identical 128B row)
    outb[(CRF_T - 1) * CRF_K + col] = (col == stag) ? 1.0f : 0.0f;

    // backtrack: lane col holds COLUMN col of bp (written by kernel B -> visible)
    for (int q0 = CRF_Q - 16; q0 >= 0; q0 -= 16) {
        unsigned int colv[16];
#pragma unroll
        for (int rr = 0; rr < 16; ++rr) colv[rr] = bpb[(q0 + rr) * CRF_K + col];
#pragma unroll
        for (int rr = 15; rr >= 0; --rr) {
#pragma unroll
            for (int bi = 3; bi >= 0; --bi) {
                const int t = (q0 + rr) * 4 + bi;
                if (t == 0) continue;   // only q0==0, rr==0, bi==0
                unsigned int dw = (unsigned int)__builtin_amdgcn_readlane((int)colv[rr], stag);
                stag = (int)((dw >> (8 * bi)) & 255u);   // plain index byte
                outb[(size_t)(t - 1) * CRF_K + col] = (col == stag) ? 1.0f : 0.0f;
            }
        }
    }
}

extern "C" void kernel_launch(void* const* d_in, const int* in_sizes, int n_in,
                              void* d_out, int out_size, void* d_ws, size_t ws_size,
                              hipStream_t stream) {
    const float* pot   = (const float*)d_in[0];   // inputs [512,2048,32] fp32
    const float* trans = (const float*)d_in[1];   // transitions [32,32] fp32
    float* out = (float*)d_out;                   // 134,217,728 B: state scratch, then one-hot
    unsigned int* bp = (unsigned int*)d_ws;       // needs 33,554,432 B (unchanged layout)

    crf_fwd<<<dim3(CRF_B),      dim3(64), 0, stream>>>(pot, trans, out);
    crf_bpk<<<dim3(CRF_B * 32), dim3(64), 0, stream>>>(out, trans, bp);
    crf_bt <<<dim3(CRF_B),      dim3(64), 0, stream>>>(bp, out);
}